// Round 13
// baseline (255.136 us; speedup 1.0000x reference)
//
#include <hip/hip_runtime.h>
#include <hip/hip_fp16.h>

// ---------------------------------------------------------------------------
// GAT 2-layer forward. N=50000 nodes, F=128, E=1.6M random edges (+N implicit
// self loops). L1: H=2,C=64 concat -> relu. L2: H=1,C=16.
//
// CSR build (atomic-minimized): memset -> {partition || gemm1} fused ->
// bucket_build (all-LDS; ushort csr; nodeseg=int2). Partition is single
// global pass (edges packed into LDS during the histogram pass).
//
// agg1s: XCD-AFFINE CHANNEL SLICING. The gather working set (xw1h, 12.8MB)
// exceeds one XCD's 4MB L2 -> measured 157MB HBM-level fetch. Split channels
// into 4 x 64B slices; slice = blockIdx&3 so with round-robin block->XCD
// dispatch each XCD touches only its 3.2MB slice (fits L2). Perf-only
// heuristic: correctness is independent of the mapping. h (relu+bias, fp16)
// is written to a global buffer; exp weights recomputed per slice (cheap).
//
// gemm2h: fp16 MFMA (16x16x32) computes xw2 = h @ w2^T + layer-2 logits.
// (R12 bug fixed: w2 staging indexed o=idx>>5,i4=(idx&31)*4 — 16 rows x 32
// float4; the R12 version read w2 OOB and overflowed lw into lh -> NaN.)
// gemm1: fp16 MFMA, LDS stride-136, fused layer-1 logits.
// Softmax without max-shift (logits bounded, fp32 exp safe; ratio identical
// to reference in exact math). xw/h stored fp16 (2^-11 rel err).
// ---------------------------------------------------------------------------

#define BSHIFT 7                 // 128 dst nodes per bucket
#define MAXB 512                 // supports N <= 65536
#define CAPMAX 6144              // LDS edge-staging bound (entries)
#define XS 136

using f16x8 = __attribute__((ext_vector_type(8))) _Float16;
using f16x4 = __attribute__((ext_vector_type(4))) _Float16;
using f32x4 = __attribute__((ext_vector_type(4))) float;

__device__ __forceinline__ float lrelu(float a) { return fmaxf(a, 0.2f * a); }

// ---------------- fused: partition (blocks 0..NB-1) + gemm1 (rest) --------

__global__ __launch_bounds__(256) void part_gemm1_kernel(
    const int* __restrict__ src, const int* __restrict__ dst,
    int* __restrict__ bincur, unsigned* __restrict__ binned,
    int E, int B, int CH, int CAP, int NB,
    const float* __restrict__ x, const float* __restrict__ w1,
    const float* __restrict__ as1, const float* __restrict__ ad1,
    __half* __restrict__ xw1h, float* __restrict__ asrc1,
    float* __restrict__ adst1, int N) {
  __shared__ __align__(16) char smem[(64 + 128) * XS * 2];  // 52224 B
  int t = threadIdx.x;

  if (blockIdx.x < (unsigned)NB) {
    // ---- partition: single global pass; pack edges into LDS ----
    int* s_h = (int*)smem;
    int* s_base = s_h + MAXB;
    int* s_cur = s_base + MAXB;
    unsigned* s_pack = (unsigned*)(s_cur + MAXB);  // CH <= 6250 -> 25 KB
    for (int i = t; i < B; i += 256) s_h[i] = 0;
    __syncthreads();
    int lo = blockIdx.x * CH;
    int cnt = min(CH, E - lo);
    for (int i = t; i < cnt; i += 256) {
      int d = dst[lo + i];
      int s = src[lo + i];
      atomicAdd(&s_h[d >> BSHIFT], 1);
      s_pack[i] = (unsigned)s | ((unsigned)(d & 127) << 16) |
                  ((unsigned)(d >> BSHIFT) << 23);
    }
    __syncthreads();
    for (int i = t; i < B; i += 256) {
      int c = s_h[i];
      s_base[i] = c ? (i * CAP + atomicAdd(&bincur[i], c)) : 0;
      s_cur[i] = 0;
    }
    __syncthreads();
    for (int i = t; i < cnt; i += 256) {
      unsigned e = s_pack[i];
      int b = e >> 23;
      int r = atomicAdd(&s_cur[b], 1);
      binned[s_base[b] + r] = e & 0x7FFFFFu;
    }
    return;
  }

  // ---- gemm1: 64-node tile, fp16 MFMA, fused logits ----
  _Float16* lx = (_Float16*)smem;
  _Float16* lw = lx + 64 * XS;
  int n0 = (blockIdx.x - NB) * 64;

#pragma unroll
  for (int j = 0; j < 8; ++j) {
    int idx = t + 256 * j;
    int nd = idx >> 5, i4 = (idx & 31) * 4;
    int gn = n0 + nd;
    float4 v = (gn < N) ? *(const float4*)&x[(size_t)gn * 128 + i4]
                        : make_float4(0.f, 0.f, 0.f, 0.f);
    f16x4 h;
    h[0] = (_Float16)v.x; h[1] = (_Float16)v.y;
    h[2] = (_Float16)v.z; h[3] = (_Float16)v.w;
    *(f16x4*)&lx[nd * XS + i4] = h;
  }
#pragma unroll
  for (int j = 0; j < 16; ++j) {
    int idx = t + 256 * j;
    int o = idx >> 5, i4 = (idx & 31) * 4;
    float4 v = *(const float4*)&w1[(size_t)o * 128 + i4];
    f16x4 h;
    h[0] = (_Float16)v.x; h[1] = (_Float16)v.y;
    h[2] = (_Float16)v.z; h[3] = (_Float16)v.w;
    *(f16x4*)&lw[o * XS + i4] = h;
  }
  __syncthreads();

  int lane = t & 63, wv = t >> 6;
  int m16 = lane & 15, q = lane >> 4;

  f32x4 acc[8];
#pragma unroll
  for (int i = 0; i < 8; ++i) acc[i] = (f32x4){0.f, 0.f, 0.f, 0.f};

#pragma unroll
  for (int c = 0; c < 4; ++c) {
    f16x8 a = *(const f16x8*)&lx[(16 * wv + m16) * XS + c * 32 + q * 8];
#pragma unroll
    for (int tt = 0; tt < 8; ++tt) {
      f16x8 b = *(const f16x8*)&lw[(tt * 16 + m16) * XS + c * 32 + q * 8];
      acc[tt] = __builtin_amdgcn_mfma_f32_16x16x32_f16(a, b, acc[tt], 0, 0, 0);
    }
  }

  // write C to this wave's own lx rows (wave-private; no barrier needed)
#pragma unroll
  for (int tt = 0; tt < 8; ++tt) {
#pragma unroll
    for (int r = 0; r < 4; ++r) {
      lx[(16 * wv + 4 * q + r) * XS + tt * 16 + m16] = (_Float16)acc[tt][r];
    }
  }

  // logits: lane -> node m16, o-part p = q (32 outputs each)
  {
    float ps = 0.f, pd = 0.f;
    int p = q;
#pragma unroll
    for (int k = 0; k < 4; ++k) {
      f16x8 hv = *(const f16x8*)&lx[(16 * wv + m16) * XS + p * 32 + k * 8];
      float4 s0 = *(const float4*)&as1[p * 32 + k * 8];
      float4 s1 = *(const float4*)&as1[p * 32 + k * 8 + 4];
      float4 d0 = *(const float4*)&ad1[p * 32 + k * 8];
      float4 d1 = *(const float4*)&ad1[p * 32 + k * 8 + 4];
      ps += (float)hv[0] * s0.x + (float)hv[1] * s0.y + (float)hv[2] * s0.z +
            (float)hv[3] * s0.w + (float)hv[4] * s1.x + (float)hv[5] * s1.y +
            (float)hv[6] * s1.z + (float)hv[7] * s1.w;
      pd += (float)hv[0] * d0.x + (float)hv[1] * d0.y + (float)hv[2] * d0.z +
            (float)hv[3] * d0.w + (float)hv[4] * d1.x + (float)hv[5] * d1.y +
            (float)hv[6] * d1.z + (float)hv[7] * d1.w;
    }
    ps += __shfl_xor(ps, 16);
    pd += __shfl_xor(pd, 16);
    int n = n0 + 16 * wv + m16;
    if (n < N && (q == 0 || q == 2)) {
      int hh = q >> 1;
      asrc1[2 * n + hh] = ps;
      adst1[2 * n + hh] = pd;
    }
  }

  // coalesced fp16 stores: 16 rows x 16 uint4 per wave -> 4 per lane
#pragma unroll
  for (int i = 0; i < 4; ++i) {
    int m = q + 4 * i;
    int n = n0 + 16 * wv + m;
    if (n < N) {
      uint4 v = *(const uint4*)&lx[(16 * wv + m) * XS + m16 * 8];
      *(uint4*)&xw1h[(size_t)n * 128 + m16 * 8] = v;
    }
  }
}

// ---------------- bucket_build: all-LDS, staged edges, ushort csr ---------

__global__ __launch_bounds__(256) void bucket_build_kernel(const unsigned* __restrict__ binned,
                                                           const int* __restrict__ bincur,
                                                           int2* __restrict__ nodeseg,
                                                           unsigned short* __restrict__ csr,
                                                           int N, int CAP) {
  __shared__ int s_deg[128];
  __shared__ int s_cur[128];
  __shared__ int s_wsum;
  __shared__ unsigned s_edges[CAPMAX];
  int b = blockIdx.x;
  int lo = b * CAP, hi = lo + bincur[b];
  int cnt = hi - lo;
  int t = threadIdx.x;
  if (t < 128) s_deg[t] = 0;
  int stg = min(cnt, CAPMAX);
  for (int i = t; i < stg; i += 256) s_edges[i] = binned[lo + i];
  __syncthreads();
  for (int i = t; i < cnt; i += 256) {
    unsigned e = (i < CAPMAX) ? s_edges[i] : binned[lo + i];
    atomicAdd(&s_deg[e >> 16], 1);
  }
  __syncthreads();
  int lane = t & 63, wv = t >> 6;
  int v = (t < 128) ? s_deg[t] : 0;
  int incl = v;
#pragma unroll
  for (int off = 1; off < 64; off <<= 1) {
    int u = __shfl_up(incl, off);
    if (lane >= off) incl += u;
  }
  if (t == 63) s_wsum = incl;  // wave-0 total
  __syncthreads();
  int excl = incl - v + ((wv == 1) ? s_wsum : 0);
  if (t < 128) {
    int node = (b << BSHIFT) + t;
    if (node < N) nodeseg[node] = make_int2(lo + excl, lo + excl + v);
    s_cur[t] = lo + excl;
  }
  __syncthreads();
  for (int i = t; i < cnt; i += 256) {
    unsigned e = (i < CAPMAX) ? s_edges[i] : binned[lo + i];
    int p = atomicAdd(&s_cur[e >> 16], 1);  // LDS atomic
    csr[p] = (unsigned short)(e & 0xFFFFu);
  }
}

// ---------------- agg1s: XCD-affine channel-sliced aggregation ------------

// slice = blockIdx&3 (64B of the 256B row); block = 4 waves, wave handles 2
// nodes sequentially. 4 rows x 16 lanes x 4B per edge, 8-edge loop.
__global__ __launch_bounds__(256) void agg1s_kernel(const __half* __restrict__ xw1h,
                                                    const float* __restrict__ asrc1,
                                                    const float* __restrict__ adst1,
                                                    const float* __restrict__ b1,
                                                    const unsigned short* __restrict__ csr,
                                                    const int2* __restrict__ nodeseg,
                                                    __half* __restrict__ hout, int N) {
  __shared__ int s_off[4][64];   // row byte offset (s * 256)
  __shared__ float s_w[4][64];   // exp weight (this slice's head)
  int lane = threadIdx.x & 63, wv = threadIdx.x >> 6;
  int slice = blockIdx.x & 3;    // round-robin dispatch -> XCD in {slice, slice+4}
  int g = blockIdx.x >> 2;
  int hs = slice >> 1;           // head of this slice
  int c16 = lane & 15;           // channel pair within slice
  int row = lane >> 4;           // 0..3 edge subgroup
  const char* xb = (const char*)xw1h + slice * 64 + c16 * 4;
  float2 bv = *(const float2*)&b1[slice * 32 + c16 * 2];

#pragma unroll
  for (int u = 0; u < 2; ++u) {
    int d = g * 8 + wv * 2 + u;
    if (d >= N) return;
    int2 seg = nodeseg[d];
    int e0 = seg.x, e1 = seg.y;
    float adv = adst1[2 * d + hs];
    float wself = __expf(lrelu(asrc1[2 * d + hs] + adv));

    float a0 = 0.f, a1 = 0.f, sum = 0.f;
    if (row == 0) {  // self edge handled once
      float2 v = __half22float2(*(const __half2*)(xb + ((size_t)d << 8)));
      a0 = wself * v.x;
      a1 = wself * v.y;
      sum = wself;
    }

    for (int base = e0; base < e1; base += 64) {
      int cnt = min(64, e1 - base);
      if (lane < cnt) {
        int s = (int)csr[base + lane];
        s_off[wv][lane] = s << 8;
        s_w[wv][lane] = __expf(lrelu(asrc1[2 * s + hs] + adv));
      }
      // wave-private LDS: same wave wrote it; no barrier needed
      int j = 0;
      for (; j + 7 < cnt; j += 8) {
        int oA = s_off[wv][j + row];
        int oB = s_off[wv][j + 4 + row];
        float wA = s_w[wv][j + row];
        float wB = s_w[wv][j + 4 + row];
        float2 vA = __half22float2(*(const __half2*)(xb + oA));
        float2 vB = __half22float2(*(const __half2*)(xb + oB));
        a0 += wA * vA.x + wB * vB.x;
        a1 += wA * vA.y + wB * vB.y;
        sum += wA + wB;
      }
      for (; j < cnt; j += 4) {
        if (row < cnt - j) {
          int oA = s_off[wv][j + row];
          float wA = s_w[wv][j + row];
          float2 vA = __half22float2(*(const __half2*)(xb + oA));
          a0 += wA * vA.x;
          a1 += wA * vA.y;
          sum += wA;
        }
      }
    }

    // butterfly across the 4 rows
    a0 += __shfl_xor(a0, 16);
    a0 += __shfl_xor(a0, 32);
    a1 += __shfl_xor(a1, 16);
    a1 += __shfl_xor(a1, 32);
    sum += __shfl_xor(sum, 16);
    sum += __shfl_xor(sum, 32);

    if (row == 0) {
      float inv = 1.f / (sum + 1e-16f);
      __half2 hv;
      hv.x = __float2half(fmaxf(a0 * inv + bv.x, 0.f));
      hv.y = __float2half(fmaxf(a1 * inv + bv.y, 0.f));
      *(__half2*)((char*)hout + ((size_t)d << 8) + slice * 64 + c16 * 4) = hv;
    }
  }
}

// ---------------- gemm2h: xw2 = h @ w2^T (fp16 MFMA) + layer-2 logits -----

__global__ __launch_bounds__(256) void gemm2h_kernel(const __half* __restrict__ hbuf,
                                                     const float* __restrict__ w2,
                                                     const float* __restrict__ as2,
                                                     const float* __restrict__ ad2,
                                                     __half* __restrict__ xw2h,
                                                     float* __restrict__ asrc2,
                                                     float* __restrict__ adst2, int N) {
  __shared__ __align__(16) _Float16 lw[16 * XS];
  __shared__ __align__(16) _Float16 lh[4][16 * XS];
  int t = threadIdx.x;
  int n0 = blockIdx.x * 64;
  // stage w2: 16 rows x 32 float4 = 512 float4s (fp32 -> fp16)
#pragma unroll
  for (int j = 0; j < 2; ++j) {
    int idx = t + 256 * j;  // 0..511
    int o = idx >> 5, i4 = (idx & 31) * 4;
    float4 v = *(const float4*)&w2[o * 128 + i4];
    f16x4 hv;
    hv[0] = (_Float16)v.x; hv[1] = (_Float16)v.y;
    hv[2] = (_Float16)v.z; hv[3] = (_Float16)v.w;
    *(f16x4*)&lw[o * XS + i4] = hv;
  }
  // stage h: 64 rows x 16 uint4
#pragma unroll
  for (int j = 0; j < 4; ++j) {
    int idx = t + 256 * j;
    int nd = idx >> 4, i8 = (idx & 15) * 8;
    int gn = n0 + nd;
    uint4 v = (gn < N) ? *(const uint4*)&hbuf[(size_t)gn * 128 + i8]
                       : make_uint4(0, 0, 0, 0);
    *(uint4*)&lh[nd >> 4][(nd & 15) * XS + i8] = v;
  }
  __syncthreads();

  int lane = t & 63, wv = t >> 6;
  int m16 = lane & 15, q = lane >> 4;
  f32x4 acc = (f32x4){0.f, 0.f, 0.f, 0.f};
#pragma unroll
  for (int c = 0; c < 4; ++c) {
    f16x8 a = *(const f16x8*)&lh[wv][m16 * XS + c * 32 + q * 8];
    f16x8 b = *(const f16x8*)&lw[m16 * XS + c * 32 + q * 8];
    acc = __builtin_amdgcn_mfma_f32_16x16x32_f16(a, b, acc, 0, 0, 0);
  }
  // lane holds D[node = 4q+r][o = m16]
  float a2v = as2[m16], d2v = ad2[m16];
#pragma unroll
  for (int r = 0; r < 4; ++r) {
    int n = n0 + wv * 16 + 4 * q + r;
    if (n < N) xw2h[(size_t)n * 16 + m16] = __float2half(acc[r]);
    float ps = acc[r] * a2v, pd = acc[r] * d2v;
#pragma unroll
    for (int k = 1; k < 16; k <<= 1) {
      ps += __shfl_xor(ps, k);
      pd += __shfl_xor(pd, k);
    }
    if (m16 == 0 && n < N) {
      asrc2[n] = ps;
      adst2[n] = pd;
    }
  }
}

// ---------------- agg2 ----------------

// wave per dst node. 8 rows x 8 lanes x 4B; 16-edge unroll = 2 loads in
// flight. Each lane owns 2 channels (half2).
__global__ __launch_bounds__(256) void agg2_kernel(const __half* __restrict__ xw2h,
                                                   const float* __restrict__ asrc2,
                                                   const float* __restrict__ adst2,
                                                   const float* __restrict__ b2,
                                                   const unsigned short* __restrict__ csr,
                                                   const int2* __restrict__ nodeseg,
                                                   float* __restrict__ out, int N) {
  __shared__ int s_off[4][64];   // row byte offset (s * 32)
  __shared__ float s_w[4][64];
  int lane = threadIdx.x & 63, wv = threadIdx.x >> 6;
  int d = blockIdx.x * 4 + wv;
  if (d >= N) return;
  int c2 = lane & 7;   // channels 2*c2, 2*c2+1
  int row = lane >> 3; // 0..7
  int2 seg = nodeseg[d];
  int e0 = seg.x, e1 = seg.y;
  float advd = adst2[d];
  float wself = __expf(lrelu(asrc2[d] + advd));
  const char* xb = (const char*)xw2h + 4 * c2;

  float a0 = 0.f, a1 = 0.f, sum = 0.f;
  if (row == 0) {
    float2 v = __half22float2(*(const __half2*)(xb + (size_t)d * 32));
    a0 = wself * v.x;
    a1 = wself * v.y;
    sum = wself;
  }
  for (int base = e0; base < e1; base += 64) {
    int cnt = min(64, e1 - base);
    if (lane < cnt) {
      int s = (int)csr[base + lane];
      s_off[wv][lane] = s << 5;
      s_w[wv][lane] = __expf(lrelu(asrc2[s] + advd));
    }
    int j = 0;
    for (; j + 15 < cnt; j += 16) {
      int o0 = s_off[wv][j + row];
      int o1 = s_off[wv][j + 8 + row];
      float w0 = s_w[wv][j + row];
      float w1 = s_w[wv][j + 8 + row];
      float2 v0 = __half22float2(*(const __half2*)(xb + o0));
      float2 v1 = __half22float2(*(const __half2*)(xb + o1));
      a0 += w0 * v0.x + w1 * v1.x;
      a1 += w0 * v0.y + w1 * v1.y;
      sum += w0 + w1;
    }
    for (; j + 7 < cnt; j += 8) {
      int o0 = s_off[wv][j + row];
      float w0 = s_w[wv][j + row];
      float2 v0 = __half22float2(*(const __half2*)(xb + o0));
      a0 += w0 * v0.x;
      a1 += w0 * v0.y;
      sum += w0;
    }
    if (row < cnt - j) {  // tail: rows 0..cnt-j-1 take one edge each
      int o0 = s_off[wv][j + row];
      float w0 = s_w[wv][j + row];
      float2 v0 = __half22float2(*(const __half2*)(xb + o0));
      a0 += w0 * v0.x;
      a1 += w0 * v0.y;
      sum += w0;
    }
  }
#pragma unroll
  for (int k = 8; k < 64; k <<= 1) {
    a0 += __shfl_xor(a0, k);
    a1 += __shfl_xor(a1, k);
    sum += __shfl_xor(sum, k);
  }
  if (lane < 8) {
    float inv = 1.f / (sum + 1e-16f);
    float2 r;
    r.x = a0 * inv + b2[2 * c2];
    r.y = a1 * inv + b2[2 * c2 + 1];
    *(float2*)&out[(size_t)d * 16 + 2 * c2] = r;
  }
}

// ---------------------------------------------------------------------------

extern "C" void kernel_launch(void* const* d_in, const int* in_sizes, int n_in,
                              void* d_out, int out_size, void* d_ws, size_t ws_size,
                              hipStream_t stream) {
  const float* x = (const float*)d_in[0];
  const int* ei = (const int*)d_in[1];
  const float* w1 = (const float*)d_in[2];
  const float* as1 = (const float*)d_in[3];
  const float* ad1 = (const float*)d_in[4];
  const float* b1 = (const float*)d_in[5];
  const float* w2 = (const float*)d_in[6];
  const float* as2 = (const float*)d_in[7];
  const float* ad2 = (const float*)d_in[8];
  const float* b2 = (const float*)d_in[9];
  float* out = (float*)d_out;

  int N = in_sizes[0] / 128;
  int E = in_sizes[1] / 2;
  const int* srcp = ei;
  const int* dstp = ei + E;

  int B = (N + (1 << BSHIFT) - 1) >> BSHIFT;  // 391 buckets (N<=65536 req'd)
  // bucket capacity: mean + 25% slack (+512), rounded to 256 (Poisson ~16sig)
  int mean = (E + B - 1) / B;
  int CAP = (mean + mean / 4 + 512 + 255) & ~255;
  const int NB = 256;  // partition blocks
  int CH = (E + NB - 1) / NB;  // 6250 -> 25 KB LDS packing buffer
  int GB = (N + 63) / 64;  // gemm1 tiles
  int NG = (N + 7) / 8;    // agg1s node octets

  char* p = (char*)d_ws;
  auto alloc = [&](size_t bytes) -> void* {
    void* r = (void*)p;
    p += (bytes + 255) & ~(size_t)255;
    return r;
  };
  __half* xw1h = (__half*)alloc((size_t)N * 128 * 2);
  __half* hbuf = (__half*)alloc((size_t)N * 128 * 2);
  float* asrc1 = (float*)alloc((size_t)N * 2 * 4);
  float* adst1 = (float*)alloc((size_t)N * 2 * 4);
  __half* xw2h = (__half*)alloc((size_t)N * 16 * 2);
  float* asrc2 = (float*)alloc((size_t)N * 4);
  float* adst2 = (float*)alloc((size_t)N * 4);
  int2* nodeseg = (int2*)alloc((size_t)N * 8);
  unsigned short* csr = (unsigned short*)alloc((size_t)B * CAP * 2);
  unsigned* binned = (unsigned*)alloc((size_t)B * CAP * 4);
  int* bincur = (int*)alloc((size_t)B * 4);

  hipMemsetAsync(bincur, 0, (size_t)B * 4, stream);
  part_gemm1_kernel<<<NB + GB, 256, 0, stream>>>(srcp, dstp, bincur, binned,
                                                 E, B, CH, CAP, NB,
                                                 x, w1, as1, ad1, xw1h, asrc1, adst1, N);
  bucket_build_kernel<<<B, 256, 0, stream>>>(binned, bincur, nodeseg, csr, N, CAP);
  agg1s_kernel<<<4 * NG, 256, 0, stream>>>(xw1h, asrc1, adst1, b1, csr, nodeseg, hbuf, N);
  gemm2h_kernel<<<(N + 63) / 64, 256, 0, stream>>>(hbuf, w2, as2, ad2,
                                                   xw2h, asrc2, adst2, N);
  agg2_kernel<<<(N + 3) / 4, 256, 0, stream>>>(xw2h, asrc2, adst2, b2, csr, nodeseg, out, N);
}

// Round 14
// 207.174 us; speedup vs baseline: 1.2315x; 1.2315x over previous
//
#include <hip/hip_runtime.h>
#include <hip/hip_fp16.h>

// ---------------------------------------------------------------------------
// GAT 2-layer forward. N=50000 nodes, F=128, E=1.6M random edges (+N implicit
// self loops). L1: H=2,C=64 concat -> relu. L2: H=1,C=16.
//
// CSR build (atomic-minimized; measured: each device-scope atomicAdd costs a
// ~64B HBM write -> minimize COUNT, not locality). Fixed-capacity bucket
// segments; bincur zeroed via memset, reservations biased by b*CAP.
// Dispatches: memset -> {partition || gemm1} (block-range fused) ->
// bucket_build (LDS-staged edges; csr stored as ushort) -> agg1 -> agg2.
//
// partition is SINGLE-global-pass: edges packed into LDS words
// (src | (d&127)<<16 | (d>>7)<<23; bucket id fits the spare 9 bits since
// B<512) during the histogram pass; the rank+scatter pass runs from LDS.
//
// gemm1: fp16 MFMA (mfma_f32_16x16x32_f16), A=x rows, B=w1 rows ([o][i] =
// B^T fed directly), LDS stride-136 fp16, fp32 accumulate, epilogue stages C
// through LDS for coalesced fp16 stores + fused logits.
//
// agg1 fuses: softmax aggregation + relu + bias (h in registers) + gemm2
// (h @ w2^T) + layer-2 logits. agg1 is gather-traffic bound (measured:
// ~157MB fetch @ ~2.5TB/s regardless of MLP depth/width/occupancy) —
// structural floor for this layout. R13 disproved XCD channel-slicing:
// 64B slices of 128B lines overfetch (FETCH 157->211MB) and replicate
// csr/logit gathers x4 — slicing cannot win for 256B rows on 4MB L2s.
// Softmax without max-shift (logits bounded, fp32 exp safe; ratio identical
// to reference in exact math). xw stored fp16 (2^-11 rel err).
// ---------------------------------------------------------------------------

#define BSHIFT 7                 // 128 dst nodes per bucket
#define MAXB 512                 // supports N <= 65536
#define CAPMAX 6144              // LDS edge-staging bound (entries)
#define XS 136

using f16x8 = __attribute__((ext_vector_type(8))) _Float16;
using f16x4 = __attribute__((ext_vector_type(4))) _Float16;
using f32x4 = __attribute__((ext_vector_type(4))) float;

__device__ __forceinline__ float lrelu(float a) { return fmaxf(a, 0.2f * a); }

// ---------------- fused: partition (blocks 0..NB-1) + gemm1 (rest) --------

__global__ __launch_bounds__(256) void part_gemm1_kernel(
    const int* __restrict__ src, const int* __restrict__ dst,
    int* __restrict__ bincur, unsigned* __restrict__ binned,
    int E, int B, int CH, int CAP, int NB,
    const float* __restrict__ x, const float* __restrict__ w1,
    const float* __restrict__ as1, const float* __restrict__ ad1,
    __half* __restrict__ xw1h, float* __restrict__ asrc1,
    float* __restrict__ adst1, int N) {
  __shared__ __align__(16) char smem[(64 + 128) * XS * 2];  // 52224 B
  int t = threadIdx.x;

  if (blockIdx.x < (unsigned)NB) {
    // ---- partition: single global pass; pack edges into LDS ----
    int* s_h = (int*)smem;
    int* s_base = s_h + MAXB;
    int* s_cur = s_base + MAXB;
    unsigned* s_pack = (unsigned*)(s_cur + MAXB);  // CH <= 6250 -> 25 KB
    for (int i = t; i < B; i += 256) s_h[i] = 0;
    __syncthreads();
    int lo = blockIdx.x * CH;
    int cnt = min(CH, E - lo);
    for (int i = t; i < cnt; i += 256) {
      int d = dst[lo + i];
      int s = src[lo + i];
      atomicAdd(&s_h[d >> BSHIFT], 1);
      s_pack[i] = (unsigned)s | ((unsigned)(d & 127) << 16) |
                  ((unsigned)(d >> BSHIFT) << 23);
    }
    __syncthreads();
    for (int i = t; i < B; i += 256) {
      int c = s_h[i];
      s_base[i] = c ? (i * CAP + atomicAdd(&bincur[i], c)) : 0;
      s_cur[i] = 0;
    }
    __syncthreads();
    for (int i = t; i < cnt; i += 256) {
      unsigned e = s_pack[i];
      int b = e >> 23;
      int r = atomicAdd(&s_cur[b], 1);
      binned[s_base[b] + r] = e & 0x7FFFFFu;
    }
    return;
  }

  // ---- gemm1: 64-node tile, fp16 MFMA, fused logits ----
  _Float16* lx = (_Float16*)smem;
  _Float16* lw = lx + 64 * XS;
  int n0 = (blockIdx.x - NB) * 64;

#pragma unroll
  for (int j = 0; j < 8; ++j) {
    int idx = t + 256 * j;
    int nd = idx >> 5, i4 = (idx & 31) * 4;
    int gn = n0 + nd;
    float4 v = (gn < N) ? *(const float4*)&x[(size_t)gn * 128 + i4]
                        : make_float4(0.f, 0.f, 0.f, 0.f);
    f16x4 h;
    h[0] = (_Float16)v.x; h[1] = (_Float16)v.y;
    h[2] = (_Float16)v.z; h[3] = (_Float16)v.w;
    *(f16x4*)&lx[nd * XS + i4] = h;
  }
#pragma unroll
  for (int j = 0; j < 16; ++j) {
    int idx = t + 256 * j;
    int o = idx >> 5, i4 = (idx & 31) * 4;
    float4 v = *(const float4*)&w1[(size_t)o * 128 + i4];
    f16x4 h;
    h[0] = (_Float16)v.x; h[1] = (_Float16)v.y;
    h[2] = (_Float16)v.z; h[3] = (_Float16)v.w;
    *(f16x4*)&lw[o * XS + i4] = h;
  }
  __syncthreads();

  int lane = t & 63, wv = t >> 6;
  int m16 = lane & 15, q = lane >> 4;

  f32x4 acc[8];
#pragma unroll
  for (int i = 0; i < 8; ++i) acc[i] = (f32x4){0.f, 0.f, 0.f, 0.f};

#pragma unroll
  for (int c = 0; c < 4; ++c) {
    f16x8 a = *(const f16x8*)&lx[(16 * wv + m16) * XS + c * 32 + q * 8];
#pragma unroll
    for (int tt = 0; tt < 8; ++tt) {
      f16x8 b = *(const f16x8*)&lw[(tt * 16 + m16) * XS + c * 32 + q * 8];
      acc[tt] = __builtin_amdgcn_mfma_f32_16x16x32_f16(a, b, acc[tt], 0, 0, 0);
    }
  }

  // write C to this wave's own lx rows (wave-private; no barrier needed)
#pragma unroll
  for (int tt = 0; tt < 8; ++tt) {
#pragma unroll
    for (int r = 0; r < 4; ++r) {
      lx[(16 * wv + 4 * q + r) * XS + tt * 16 + m16] = (_Float16)acc[tt][r];
    }
  }

  // logits: lane -> node m16, o-part p = q (32 outputs each)
  {
    float ps = 0.f, pd = 0.f;
    int p = q;
#pragma unroll
    for (int k = 0; k < 4; ++k) {
      f16x8 hv = *(const f16x8*)&lx[(16 * wv + m16) * XS + p * 32 + k * 8];
      float4 s0 = *(const float4*)&as1[p * 32 + k * 8];
      float4 s1 = *(const float4*)&as1[p * 32 + k * 8 + 4];
      float4 d0 = *(const float4*)&ad1[p * 32 + k * 8];
      float4 d1 = *(const float4*)&ad1[p * 32 + k * 8 + 4];
      ps += (float)hv[0] * s0.x + (float)hv[1] * s0.y + (float)hv[2] * s0.z +
            (float)hv[3] * s0.w + (float)hv[4] * s1.x + (float)hv[5] * s1.y +
            (float)hv[6] * s1.z + (float)hv[7] * s1.w;
      pd += (float)hv[0] * d0.x + (float)hv[1] * d0.y + (float)hv[2] * d0.z +
            (float)hv[3] * d0.w + (float)hv[4] * d1.x + (float)hv[5] * d1.y +
            (float)hv[6] * d1.z + (float)hv[7] * d1.w;
    }
    ps += __shfl_xor(ps, 16);
    pd += __shfl_xor(pd, 16);
    int n = n0 + 16 * wv + m16;
    if (n < N && (q == 0 || q == 2)) {
      int hh = q >> 1;
      asrc1[2 * n + hh] = ps;
      adst1[2 * n + hh] = pd;
    }
  }

  // coalesced fp16 stores: 16 rows x 16 uint4 per wave -> 4 per lane
#pragma unroll
  for (int i = 0; i < 4; ++i) {
    int m = q + 4 * i;
    int n = n0 + 16 * wv + m;
    if (n < N) {
      uint4 v = *(const uint4*)&lx[(16 * wv + m) * XS + m16 * 8];
      *(uint4*)&xw1h[(size_t)n * 128 + m16 * 8] = v;
    }
  }
}

// ---------------- bucket_build: all-LDS, staged edges, ushort csr ---------

__global__ __launch_bounds__(256) void bucket_build_kernel(const unsigned* __restrict__ binned,
                                                           const int* __restrict__ bincur,
                                                           int2* __restrict__ nodeseg,
                                                           unsigned short* __restrict__ csr,
                                                           int N, int CAP) {
  __shared__ int s_deg[128];
  __shared__ int s_cur[128];
  __shared__ int s_wsum;
  __shared__ unsigned s_edges[CAPMAX];
  int b = blockIdx.x;
  int lo = b * CAP, hi = lo + bincur[b];
  int cnt = hi - lo;
  int t = threadIdx.x;
  if (t < 128) s_deg[t] = 0;
  int stg = min(cnt, CAPMAX);
  for (int i = t; i < stg; i += 256) s_edges[i] = binned[lo + i];
  __syncthreads();
  for (int i = t; i < cnt; i += 256) {
    unsigned e = (i < CAPMAX) ? s_edges[i] : binned[lo + i];
    atomicAdd(&s_deg[e >> 16], 1);
  }
  __syncthreads();
  int lane = t & 63, wv = t >> 6;
  int v = (t < 128) ? s_deg[t] : 0;
  int incl = v;
#pragma unroll
  for (int off = 1; off < 64; off <<= 1) {
    int u = __shfl_up(incl, off);
    if (lane >= off) incl += u;
  }
  if (t == 63) s_wsum = incl;  // wave-0 total
  __syncthreads();
  int excl = incl - v + ((wv == 1) ? s_wsum : 0);
  if (t < 128) {
    int node = (b << BSHIFT) + t;
    if (node < N) nodeseg[node] = make_int2(lo + excl, lo + excl + v);
    s_cur[t] = lo + excl;
  }
  __syncthreads();
  for (int i = t; i < cnt; i += 256) {
    unsigned e = (i < CAPMAX) ? s_edges[i] : binned[lo + i];
    int p = atomicAdd(&s_cur[e >> 16], 1);  // LDS atomic
    csr[p] = (unsigned short)(e & 0xFFFFu);
  }
}

// ---------------- agg1: aggregation + fused relu/bias/gemm2/logits --------

// wave per dst node. 4 rows x 16 lanes x 16B (8-edge loop, 2 loads in
// flight — measured: L2-miss BW bound; deeper MLP doesn't help).
__global__ __launch_bounds__(256) void agg1_kernel(const __half* __restrict__ xw1h,
                                                   const float* __restrict__ asrc1,
                                                   const float* __restrict__ adst1,
                                                   const float* __restrict__ b1,
                                                   const float* __restrict__ w2,
                                                   const float* __restrict__ as2,
                                                   const float* __restrict__ ad2,
                                                   const unsigned short* __restrict__ csr,
                                                   const int2* __restrict__ nodeseg,
                                                   __half* __restrict__ xw2h,
                                                   float* __restrict__ asrc2,
                                                   float* __restrict__ adst2, int N) {
  __shared__ int s_off[4][64];    // row byte offset (s * 256)
  __shared__ float2 s_w[4][64];   // exp weights per head
  int lane = threadIdx.x & 63, wv = threadIdx.x >> 6;
  int d = blockIdx.x * 4 + wv;
  if (d >= N) return;
  int c8 = lane & 15;   // channels 8*c8 .. 8*c8+7
  int row = lane >> 4;  // 0..3 edge subgroup
  int head = c8 >> 3;   // head of these channels
  int2 seg = nodeseg[d];
  int e0 = seg.x, e1 = seg.y;
  float2 asv = *(const float2*)&asrc1[2 * d];
  float2 adv = *(const float2*)&adst1[2 * d];
  float wself = __expf(lrelu(head ? (asv.y + adv.y) : (asv.x + adv.x)));

  const char* xb = (const char*)xw1h + 16 * c8;  // channel base

  float a[8];
  float sum = 0.f;
#pragma unroll
  for (int k = 0; k < 8; ++k) a[k] = 0.f;
  if (row == 0) {  // self edge handled once, by row 0
    uint4 r = *(const uint4*)(xb + ((size_t)d << 8));
    const __half2* hp = (const __half2*)&r;
#pragma unroll
    for (int k = 0; k < 4; ++k) {
      float2 v = __half22float2(hp[k]);
      a[2 * k] = wself * v.x;
      a[2 * k + 1] = wself * v.y;
    }
    sum = wself;
  }

  for (int base = e0; base < e1; base += 64) {
    int cnt = min(64, e1 - base);
    if (lane < cnt) {
      int s = (int)csr[base + lane];
      float2 aa = *(const float2*)&asrc1[2 * s];
      s_off[wv][lane] = s << 8;
      float2 w;
      w.x = __expf(lrelu(aa.x + adv.x));
      w.y = __expf(lrelu(aa.y + adv.y));
      s_w[wv][lane] = w;
    }
    // wave-private LDS: same wave wrote it; no barrier needed
    int j = 0;
    for (; j + 7 < cnt; j += 8) {
      int oA = s_off[wv][j + row];
      int oB = s_off[wv][j + 4 + row];
      float wA = ((const float*)&s_w[wv][j + row])[head];
      float wB = ((const float*)&s_w[wv][j + 4 + row])[head];
      uint4 rA = *(const uint4*)(xb + oA);
      uint4 rB = *(const uint4*)(xb + oB);
      const __half2* hA = (const __half2*)&rA;
      const __half2* hB = (const __half2*)&rB;
#pragma unroll
      for (int k = 0; k < 4; ++k) {
        float2 vA = __half22float2(hA[k]);
        float2 vB = __half22float2(hB[k]);
        a[2 * k] += wA * vA.x + wB * vB.x;
        a[2 * k + 1] += wA * vA.y + wB * vB.y;
      }
      sum += wA + wB;
    }
    for (; j < cnt; j += 4) {
      if (row < cnt - j) {
        int oA = s_off[wv][j + row];
        float wA = ((const float*)&s_w[wv][j + row])[head];
        uint4 rA = *(const uint4*)(xb + oA);
        const __half2* hA = (const __half2*)&rA;
#pragma unroll
        for (int k = 0; k < 4; ++k) {
          float2 vA = __half22float2(hA[k]);
          a[2 * k] += wA * vA.x;
          a[2 * k + 1] += wA * vA.y;
        }
        sum += wA;
      }
    }
  }

  // butterfly across the 4 rows -> every lane holds full sums for its c8
#pragma unroll
  for (int k = 0; k < 8; ++k) {
    a[k] += __shfl_xor(a[k], 16);
    a[k] += __shfl_xor(a[k], 32);
  }
  sum += __shfl_xor(sum, 16);
  sum += __shfl_xor(sum, 32);

  // h (relu'd, biased) in registers — every lane holds 8 channels
  float inv = 1.f / (sum + 1e-16f);
  float4 blo = *(const float4*)&b1[8 * c8];
  float4 bhi = *(const float4*)&b1[8 * c8 + 4];
  float h[8];
  h[0] = fmaxf(a[0] * inv + blo.x, 0.f);
  h[1] = fmaxf(a[1] * inv + blo.y, 0.f);
  h[2] = fmaxf(a[2] * inv + blo.z, 0.f);
  h[3] = fmaxf(a[3] * inv + blo.w, 0.f);
  h[4] = fmaxf(a[4] * inv + bhi.x, 0.f);
  h[5] = fmaxf(a[5] * inv + bhi.y, 0.f);
  h[6] = fmaxf(a[6] * inv + bhi.z, 0.f);
  h[7] = fmaxf(a[7] * inv + bhi.w, 0.f);

  // fused gemm2: row r computes xw2 channels r*4..r*4+3 (butterfly over 16)
  float p[4];
#pragma unroll
  for (int cc = 0; cc < 4; ++cc) {
    const float4 wlo = *(const float4*)&w2[(row * 4 + cc) * 128 + 8 * c8];
    const float4 whi = *(const float4*)&w2[(row * 4 + cc) * 128 + 8 * c8 + 4];
    p[cc] = h[0] * wlo.x + h[1] * wlo.y + h[2] * wlo.z + h[3] * wlo.w +
            h[4] * whi.x + h[5] * whi.y + h[6] * whi.z + h[7] * whi.w;
#pragma unroll
    for (int k = 1; k < 16; k <<= 1) p[cc] += __shfl_xor(p[cc], k);
  }
  float qs = 0.f, qd = 0.f;
#pragma unroll
  for (int cc = 0; cc < 4; ++cc) {
    qs += p[cc] * as2[row * 4 + cc];
    qd += p[cc] * ad2[row * 4 + cc];
  }
  qs += __shfl_xor(qs, 16);
  qs += __shfl_xor(qs, 32);
  qd += __shfl_xor(qd, 16);
  qd += __shfl_xor(qd, 32);
  if (lane == 0) {
    asrc2[d] = qs;
    adst2[d] = qd;
  }
  if (c8 == 0) {  // one lane per row stores its 4 channels (8B)
    union {
      __half hh[4];
      uint2 u;
    } pk;
#pragma unroll
    for (int cc = 0; cc < 4; ++cc) pk.hh[cc] = __float2half(p[cc]);
    *(uint2*)&xw2h[(size_t)d * 16 + row * 4] = pk.u;
  }
}

// ---------------- agg2 ----------------

// wave per dst node. 8 rows x 8 lanes x 4B; 16-edge unroll = 2 loads in
// flight. Each lane owns 2 channels (half2).
__global__ __launch_bounds__(256) void agg2_kernel(const __half* __restrict__ xw2h,
                                                   const float* __restrict__ asrc2,
                                                   const float* __restrict__ adst2,
                                                   const float* __restrict__ b2,
                                                   const unsigned short* __restrict__ csr,
                                                   const int2* __restrict__ nodeseg,
                                                   float* __restrict__ out, int N) {
  __shared__ int s_off[4][64];   // row byte offset (s * 32)
  __shared__ float s_w[4][64];
  int lane = threadIdx.x & 63, wv = threadIdx.x >> 6;
  int d = blockIdx.x * 4 + wv;
  if (d >= N) return;
  int c2 = lane & 7;   // channels 2*c2, 2*c2+1
  int row = lane >> 3; // 0..7
  int2 seg = nodeseg[d];
  int e0 = seg.x, e1 = seg.y;
  float advd = adst2[d];
  float wself = __expf(lrelu(asrc2[d] + advd));
  const char* xb = (const char*)xw2h + 4 * c2;

  float a0 = 0.f, a1 = 0.f, sum = 0.f;
  if (row == 0) {
    float2 v = __half22float2(*(const __half2*)(xb + (size_t)d * 32));
    a0 = wself * v.x;
    a1 = wself * v.y;
    sum = wself;
  }
  for (int base = e0; base < e1; base += 64) {
    int cnt = min(64, e1 - base);
    if (lane < cnt) {
      int s = (int)csr[base + lane];
      s_off[wv][lane] = s << 5;
      s_w[wv][lane] = __expf(lrelu(asrc2[s] + advd));
    }
    int j = 0;
    for (; j + 15 < cnt; j += 16) {
      int o0 = s_off[wv][j + row];
      int o1 = s_off[wv][j + 8 + row];
      float w0 = s_w[wv][j + row];
      float w1 = s_w[wv][j + 8 + row];
      float2 v0 = __half22float2(*(const __half2*)(xb + o0));
      float2 v1 = __half22float2(*(const __half2*)(xb + o1));
      a0 += w0 * v0.x + w1 * v1.x;
      a1 += w0 * v0.y + w1 * v1.y;
      sum += w0 + w1;
    }
    for (; j + 7 < cnt; j += 8) {
      int o0 = s_off[wv][j + row];
      float w0 = s_w[wv][j + row];
      float2 v0 = __half22float2(*(const __half2*)(xb + o0));
      a0 += w0 * v0.x;
      a1 += w0 * v0.y;
      sum += w0;
    }
    if (row < cnt - j) {  // tail: rows 0..cnt-j-1 take one edge each
      int o0 = s_off[wv][j + row];
      float w0 = s_w[wv][j + row];
      float2 v0 = __half22float2(*(const __half2*)(xb + o0));
      a0 += w0 * v0.x;
      a1 += w0 * v0.y;
      sum += w0;
    }
  }
#pragma unroll
  for (int k = 8; k < 64; k <<= 1) {
    a0 += __shfl_xor(a0, k);
    a1 += __shfl_xor(a1, k);
    sum += __shfl_xor(sum, k);
  }
  if (lane < 8) {
    float inv = 1.f / (sum + 1e-16f);
    float2 r;
    r.x = a0 * inv + b2[2 * c2];
    r.y = a1 * inv + b2[2 * c2 + 1];
    *(float2*)&out[(size_t)d * 16 + 2 * c2] = r;
  }
}

// ---------------------------------------------------------------------------

extern "C" void kernel_launch(void* const* d_in, const int* in_sizes, int n_in,
                              void* d_out, int out_size, void* d_ws, size_t ws_size,
                              hipStream_t stream) {
  const float* x = (const float*)d_in[0];
  const int* ei = (const int*)d_in[1];
  const float* w1 = (const float*)d_in[2];
  const float* as1 = (const float*)d_in[3];
  const float* ad1 = (const float*)d_in[4];
  const float* b1 = (const float*)d_in[5];
  const float* w2 = (const float*)d_in[6];
  const float* as2 = (const float*)d_in[7];
  const float* ad2 = (const float*)d_in[8];
  const float* b2 = (const float*)d_in[9];
  float* out = (float*)d_out;

  int N = in_sizes[0] / 128;
  int E = in_sizes[1] / 2;
  const int* srcp = ei;
  const int* dstp = ei + E;

  int B = (N + (1 << BSHIFT) - 1) >> BSHIFT;  // 391 buckets (N<=65536 req'd)
  // bucket capacity: mean + 25% slack (+512), rounded to 256 (Poisson ~16sig)
  int mean = (E + B - 1) / B;
  int CAP = (mean + mean / 4 + 512 + 255) & ~255;
  const int NB = 256;  // partition blocks
  int CH = (E + NB - 1) / NB;  // 6250 -> 25 KB LDS packing buffer
  int GB = (N + 63) / 64;  // gemm1 tiles

  char* p = (char*)d_ws;
  auto alloc = [&](size_t bytes) -> void* {
    void* r = (void*)p;
    p += (bytes + 255) & ~(size_t)255;
    return r;
  };
  __half* xw1h = (__half*)alloc((size_t)N * 128 * 2);
  float* asrc1 = (float*)alloc((size_t)N * 2 * 4);
  float* adst1 = (float*)alloc((size_t)N * 2 * 4);
  __half* xw2h = (__half*)alloc((size_t)N * 16 * 2);
  float* asrc2 = (float*)alloc((size_t)N * 4);
  float* adst2 = (float*)alloc((size_t)N * 4);
  int2* nodeseg = (int2*)alloc((size_t)N * 8);
  unsigned short* csr = (unsigned short*)alloc((size_t)B * CAP * 2);
  unsigned* binned = (unsigned*)alloc((size_t)B * CAP * 4);
  int* bincur = (int*)alloc((size_t)B * 4);

  hipMemsetAsync(bincur, 0, (size_t)B * 4, stream);
  part_gemm1_kernel<<<NB + GB, 256, 0, stream>>>(srcp, dstp, bincur, binned,
                                                 E, B, CH, CAP, NB,
                                                 x, w1, as1, ad1, xw1h, asrc1, adst1, N);
  bucket_build_kernel<<<B, 256, 0, stream>>>(binned, bincur, nodeseg, csr, N, CAP);
  agg1_kernel<<<(N + 3) / 4, 256, 0, stream>>>(xw1h, asrc1, adst1, b1, w2, as2, ad2,
                                               csr, nodeseg, xw2h, asrc2, adst2, N);
  agg2_kernel<<<(N + 3) / 4, 256, 0, stream>>>(xw2h, asrc2, adst2, b2, csr, nodeseg, out, N);
}